// Round 7
// baseline (824.014 us; speedup 1.0000x reference)
//
#include <hip/hip_runtime.h>
#include <hip/hip_bf16.h>
#include <stdint.h>
#include <math.h>

#define N_NODES 8192
#define FDIM 128
#define LRELU_ALPHA 0.2f
#define BETA 0.3f
#define NEGV -9000000000000000.0f
#define THR 8.0f
#define NJQ 4                     // j-quarters (one per XCD pair)

typedef __attribute__((ext_vector_type(8))) short bf16x8;
typedef __attribute__((ext_vector_type(4))) float f32x4;
typedef __attribute__((ext_vector_type(4))) long long64x4;

__device__ __forceinline__ uint16_t f2b(float x) {
  union { float f; uint32_t u; } v; v.f = x;
  uint32_t r = v.u + 0x7FFFu + ((v.u >> 16) & 1u);
  return (uint16_t)(r >> 16);
}

// ---------------------------------------------------------------------------
// prep_wh: Wh = h @ w.  Writes Wh fp32, Wh bf16 (row-major), Wh^T bf16.
// ---------------------------------------------------------------------------
__global__ void __launch_bounds__(256) prep_wh(
    const float* __restrict__ h, const float* __restrict__ w,
    float* __restrict__ whf, uint16_t* __restrict__ whb,
    uint16_t* __restrict__ whtb) {
  __shared__ float hs[32][128];
  const int t = threadIdx.x;
  const int rb = blockIdx.x * 32;
#pragma unroll
  for (int k = 0; k < 16; ++k) {
    int idx = t + k * 256;
    int r = idx >> 7, c = idx & 127;
    hs[r][c] = h[(size_t)(rb + r) * FDIM + c];
  }
  __syncthreads();
  const int c = t & 127;
  const int half = t >> 7;
  const int r0 = half * 16;
  float acc[16];
#pragma unroll
  for (int k = 0; k < 16; ++k) acc[k] = 0.f;
  for (int kk = 0; kk < 128; ++kk) {
    float wv = w[kk * FDIM + c];
#pragma unroll
    for (int k = 0; k < 16; ++k) acc[k] += hs[r0 + k][kk] * wv;
  }
  uint16_t tb[16];
#pragma unroll
  for (int k = 0; k < 16; ++k) {
    int r = rb + r0 + k;
    whf[(size_t)r * FDIM + c] = acc[k];
    uint16_t b = f2b(acc[k]);
    whb[(size_t)r * FDIM + c] = b;
    tb[k] = b;
  }
  uint16_t* dst = whtb + (size_t)c * N_NODES + rb + r0;
  bf16x8 v0, v1;
#pragma unroll
  for (int k = 0; k < 8; ++k) { v0[k] = (short)tb[k]; v1[k] = (short)tb[k + 8]; }
  *(bf16x8*)(dst) = v0;
  *(bf16x8*)(dst + 8) = v1;
}

// ---------------------------------------------------------------------------
// prep_s1: s1[i] = dot(Wh[i], a1[i]);  a2 -> bf16.
// ---------------------------------------------------------------------------
__global__ void __launch_bounds__(256) prep_s1(
    const float* __restrict__ whf, const float* __restrict__ a,
    float* __restrict__ s1, uint16_t* __restrict__ a2b) {
  const int t = threadIdx.x;
  const int rb = blockIdx.x * 32;
  const int wv = t >> 6;
  const int lane = t & 63;
  const int r = rb + wv * 8 + (lane >> 3);
  const int c0 = (lane & 7) * 16;
  float s = 0.f;
#pragma unroll
  for (int k = 0; k < 16; ++k) {
    s += whf[(size_t)r * FDIM + c0 + k] * a[(size_t)r * 256 + c0 + k];
  }
  s += __shfl_xor(s, 1);
  s += __shfl_xor(s, 2);
  s += __shfl_xor(s, 4);
  if ((lane & 7) == 0) s1[r] = s;
#pragma unroll
  for (int k = 0; k < 16; ++k) {
    int idx = t + k * 256;
    int rr = idx >> 7, cc = idx & 127;
    a2b[(size_t)(rb + rr) * FDIM + cc] = f2b(a[(size_t)(rb + rr) * 256 + 128 + cc]);
  }
}

// ---------------------------------------------------------------------------
// pack_adj: adj (int32 0/1, 256MB) -> bitmask (8MB).  x4 unrolled stream.
// ---------------------------------------------------------------------------
__global__ void __launch_bounds__(256) pack_adj(
    const int* __restrict__ adj, uint32_t* __restrict__ bits) {
  const int wid = (blockIdx.x * 256 + threadIdx.x) >> 6;
  const int lane = threadIdx.x & 63;
  for (int g = 0; g < 128; g += 4) {
    size_t gi = (size_t)wid * 128 + g;
    int v0 = adj[(gi + 0) * 64 + lane];
    int v1 = adj[(gi + 1) * 64 + lane];
    int v2 = adj[(gi + 2) * 64 + lane];
    int v3 = adj[(gi + 3) * 64 + lane];
    unsigned long long m0 = __ballot(v0 > 0);
    unsigned long long m1 = __ballot(v1 > 0);
    unsigned long long m2 = __ballot(v2 > 0);
    unsigned long long m3 = __ballot(v3 > 0);
    if (lane == 0) {
      long64x4 pk;
      pk[0] = (long)m0; pk[1] = (long)m1; pk[2] = (long)m2; pk[3] = (long)m3;
      *(long64x4*)(bits + gi * 2) = pk;
    }
  }
}

// ---------------------------------------------------------------------------
// gat_main: ITILE=32, 8 waves, 4 j-quarters (XCD-pair partitioned).
// LDS trimmed to ~56KB so 2 blocks/CU are resident (16 waves/CU).
// grid 1024 blocks x 512 thr.
// ---------------------------------------------------------------------------
__global__ void __launch_bounds__(512, 4) gat_main(
    const uint32_t* __restrict__ adjw, const uint16_t* __restrict__ whb,
    const uint16_t* __restrict__ whtb, const uint16_t* __restrict__ a2b,
    const float* __restrict__ s1,
    float* __restrict__ pm, float* __restrict__ pl, float* __restrict__ pO) {
  __shared__ float O_lds[8][16][64];                     // 32 KB (4-pass merge)
  __shared__ __align__(16) uint16_t plds[8][32][40];     // 20.5 KB, pitch 80B
  __shared__ float m_lds[8][32], l_lds[8][32];
  __shared__ float ew_lds[8][32];

  const int bid = blockIdx.x;
  const int xcd = bid & 7;                  // assumed XCD round-robin
  const int jq = xcd >> 1;                  // j-quarter owned by this XCD pair
  const int ib = ((bid >> 3) << 1) | (xcd & 1);
  const int ibase = ib * 32;
  const int jqb = jq * (N_NODES / NJQ);

  const int tid = threadIdx.x;
  const int wv = tid >> 6;
  const int lane = tid & 63;
  const int ln = lane & 15;
  const int lg = lane >> 4;

  bf16x8 af[2][4];
#pragma unroll
  for (int it = 0; it < 2; ++it)
#pragma unroll
    for (int ks = 0; ks < 4; ++ks)
      af[it][ks] = *(const bf16x8*)(a2b + (size_t)(ibase + it * 16 + ln) * FDIM + ks * 32 + lg * 8);

  float s1v[2][4];
#pragma unroll
  for (int it = 0; it < 2; ++it)
#pragma unroll
    for (int r = 0; r < 4; ++r)
      s1v[it][r] = s1[ibase + it * 16 + lg * 4 + r];

  const uint32_t* adjbase = adjw + (size_t)(ibase + lg * 4) * (N_NODES / 32);

  float mrun[2][4], lsum[2][4];
#pragma unroll
  for (int it = 0; it < 2; ++it)
#pragma unroll
    for (int r = 0; r < 4; ++r) { mrun[it][r] = -INFINITY; lsum[it][r] = 0.f; }
  f32x4 O[2][8];
#pragma unroll
  for (int it = 0; it < 2; ++it)
#pragma unroll
    for (int ft = 0; ft < 8; ++ft) O[it][ft] = (f32x4){0.f, 0.f, 0.f, 0.f};

  const int j0 = jqb + wv * (N_NODES / NJQ / 8);          // 256 j per wave
  for (int jb = j0; jb < j0 + N_NODES / NJQ / 8; jb += 32) {
    const int wi = jb >> 5;
    uint32_t aw[2][4];
#pragma unroll
    for (int it = 0; it < 2; ++it)
#pragma unroll
      for (int r = 0; r < 4; ++r)
        aw[it][r] = adjbase[(size_t)(it * 16 + r) * (N_NODES / 32) + wi];

    f32x4 sacc[2][2];
#pragma unroll
    for (int it = 0; it < 2; ++it)
#pragma unroll
      for (int nt = 0; nt < 2; ++nt) sacc[it][nt] = (f32x4){0.f, 0.f, 0.f, 0.f};
#pragma unroll
    for (int nt = 0; nt < 2; ++nt)
#pragma unroll
      for (int ks = 0; ks < 4; ++ks) {
        bf16x8 b = *(const bf16x8*)(whb + (size_t)(jb + nt * 16 + ln) * FDIM + ks * 32 + lg * 8);
        sacc[0][nt] = __builtin_amdgcn_mfma_f32_16x16x32_bf16(af[0][ks], b, sacc[0][nt], 0, 0, 0);
        sacc[1][nt] = __builtin_amdgcn_mfma_f32_16x16x32_bf16(af[1][ks], b, sacc[1][nt], 0, 0, 0);
      }

    float e[2][2][4];
#pragma unroll
    for (int it = 0; it < 2; ++it)
#pragma unroll
      for (int nt = 0; nt < 2; ++nt)
#pragma unroll
        for (int r = 0; r < 4; ++r) {
          float v = s1v[it][r] + sacc[it][nt][r];
          v = (v > 0.f) ? v : LRELU_ALPHA * v;
          uint32_t bit = (aw[it][r] >> (nt * 16 + ln)) & 1u;
          e[it][nt][r] = bit ? v : NEGV;
        }

    bool upd = false;
#pragma unroll
    for (int it = 0; it < 2; ++it)
#pragma unroll
      for (int r = 0; r < 4; ++r)
        upd |= (e[it][0][r] > mrun[it][r] + THR) || (e[it][1][r] > mrun[it][r] + THR);
    if (__any(upd)) {
#pragma unroll
      for (int it = 0; it < 2; ++it) {
        float mx[4];
#pragma unroll
        for (int r = 0; r < 4; ++r) mx[r] = fmaxf(e[it][0][r], e[it][1][r]);
#pragma unroll
        for (int off = 1; off <= 8; off <<= 1)
#pragma unroll
          for (int r = 0; r < 4; ++r) mx[r] = fmaxf(mx[r], __shfl_xor(mx[r], off));
#pragma unroll
        for (int r = 0; r < 4; ++r) {
          float mn = fmaxf(mrun[it][r], mx[r]);
          float al = __expf(mrun[it][r] - mn);
          mrun[it][r] = mn;
          lsum[it][r] *= al;
#pragma unroll
          for (int ft = 0; ft < 8; ++ft) O[it][ft][r] *= al;
        }
      }
    }

#pragma unroll
    for (int it = 0; it < 2; ++it)
#pragma unroll
      for (int nt = 0; nt < 2; ++nt)
#pragma unroll
        for (int r = 0; r < 4; ++r) {
          float p = __expf(e[it][nt][r] - mrun[it][r]);
          lsum[it][r] += p;
          plds[wv][it * 16 + lg * 4 + r][nt * 16 + ln] = f2b(p);
        }

    bf16x8 pa0 = *(const bf16x8*)&plds[wv][ln][lg * 8];
    bf16x8 pa1 = *(const bf16x8*)&plds[wv][16 + ln][lg * 8];

#pragma unroll
    for (int ft = 0; ft < 8; ++ft) {
      bf16x8 bv = *(const bf16x8*)(whtb + (size_t)(ft * 16 + ln) * N_NODES + jb + lg * 8);
      O[0][ft] = __builtin_amdgcn_mfma_f32_16x16x32_bf16(pa0, bv, O[0][ft], 0, 0, 0);
      O[1][ft] = __builtin_amdgcn_mfma_f32_16x16x32_bf16(pa1, bv, O[1][ft], 0, 0, 0);
    }
  }

#pragma unroll
  for (int off = 1; off <= 8; off <<= 1)
#pragma unroll
    for (int it = 0; it < 2; ++it)
#pragma unroll
      for (int r = 0; r < 4; ++r) lsum[it][r] += __shfl_xor(lsum[it][r], off);

  if (ln == 0) {
#pragma unroll
    for (int it = 0; it < 2; ++it)
#pragma unroll
      for (int r = 0; r < 4; ++r) {
        m_lds[wv][it * 16 + lg * 4 + r] = mrun[it][r];
        l_lds[wv][it * 16 + lg * 4 + r] = lsum[it][r];
      }
  }
  __syncthreads();

  if (tid < 32) {
    float ms = -INFINITY;
#pragma unroll
    for (int w2 = 0; w2 < 8; ++w2) ms = fmaxf(ms, m_lds[w2][tid]);
    float L = 0.f;
#pragma unroll
    for (int w2 = 0; w2 < 8; ++w2) {
      float x = __expf(m_lds[w2][tid] - ms);
      ew_lds[w2][tid] = x;
      L += l_lds[w2][tid] * x;
    }
    pm[(size_t)jq * N_NODES + ibase + tid] = ms;
    pl[(size_t)jq * N_NODES + ibase + tid] = L;
  }
  __syncthreads();

  // 4-pass merge of the 8 waves' O into per-quarter partials:
  // 2 row-halves (h) x 2 column-halves (cg), 16 rows x 64 cols per pass.
#pragma unroll
  for (int h = 0; h < 2; ++h)
#pragma unroll
    for (int cg = 0; cg < 2; ++cg) {
#pragma unroll
      for (int f2 = 0; f2 < 4; ++f2)
#pragma unroll
        for (int r = 0; r < 4; ++r)
          O_lds[wv][lg * 4 + r][f2 * 16 + ln] = O[h][cg * 4 + f2][r];
      __syncthreads();
#pragma unroll
      for (int k = 0; k < 2; ++k) {
        int idx = tid + k * 512;          // 0..1023 = 16 rows x 64
        int r = idx >> 6, f = idx & 63;
        float v = 0.f;
#pragma unroll
        for (int w2 = 0; w2 < 8; ++w2) v += O_lds[w2][r][f] * ew_lds[w2][h * 16 + r];
        int row = ibase + h * 16 + r;
        pO[((size_t)jq * N_NODES + row) * FDIM + cg * 64 + f] = v;
      }
      __syncthreads();
    }
}

// ---------------------------------------------------------------------------
// merge_out: combine the 4 j-quarter partials, normalize, BETA/ELU epilogue.
// ---------------------------------------------------------------------------
__global__ void __launch_bounds__(256) merge_out(
    const float* __restrict__ pm, const float* __restrict__ pl,
    const float* __restrict__ pO, const float* __restrict__ whf,
    float* __restrict__ out) {
  const int idx = blockIdx.x * 256 + threadIdx.x;   // 0 .. N*F-1
  const int row = idx >> 7;
  float m[NJQ];
#pragma unroll
  for (int q = 0; q < NJQ; ++q) m[q] = pm[q * N_NODES + row];
  float M = fmaxf(fmaxf(m[0], m[1]), fmaxf(m[2], m[3]));
  float ew[NJQ];
  float L = 0.f;
#pragma unroll
  for (int q = 0; q < NJQ; ++q) {
    ew[q] = __expf(m[q] - M);
    L += pl[q * N_NODES + row] * ew[q];
  }
  float v = 0.f;
#pragma unroll
  for (int q = 0; q < NJQ; ++q)
    v += pO[(size_t)q * N_NODES * FDIM + idx] * ew[q];
  v /= L;
  v += BETA * whf[idx];
  out[idx] = (v > 0.f) ? v : (__expf(v) - 1.0f);
}

// ---------------------------------------------------------------------------
extern "C" void kernel_launch(void* const* d_in, const int* in_sizes, int n_in,
                              void* d_out, int out_size, void* d_ws, size_t ws_size,
                              hipStream_t stream) {
  const float* h   = (const float*)d_in[0];
  const int*   adj = (const int*)d_in[1];
  const float* w   = (const float*)d_in[3];
  const float* a   = (const float*)d_in[4];
  float* out = (float*)d_out;

  char* ws = (char*)d_ws;
  float*    whf  = (float*)ws;                               // 4 MB
  uint16_t* whb  = (uint16_t*)(ws + (4 << 20));              // 2 MB
  uint16_t* whtb = (uint16_t*)(ws + (6 << 20));              // 2 MB
  uint16_t* a2b  = (uint16_t*)(ws + (8 << 20));              // 2 MB
  float*    s1   = (float*)(ws + (10 << 20));                // 32 KB
  uint32_t* adjw = (uint32_t*)(ws + (10 << 20) + (1 << 19)); // 8 MB bitmask
  float*    pm   = (float*)(ws + (18 << 20) + (1 << 19));    // 128 KB
  float*    pl   = (float*)(ws + (18 << 20) + (1 << 19) + (1 << 17)); // 128 KB
  float*    pO   = (float*)(ws + (19 << 20));                // 16 MB

  prep_wh<<<N_NODES / 32, 256, 0, stream>>>(h, w, whf, whb, whtb);
  prep_s1<<<N_NODES / 32, 256, 0, stream>>>(whf, a, s1, a2b);
  pack_adj<<<2048, 256, 0, stream>>>(adj, adjw);
  gat_main<<<(N_NODES / 32) * NJQ, 512, 0, stream>>>(adjw, whb, whtb, a2b, s1, pm, pl, pO);
  merge_out<<<N_NODES * FDIM / 256, 256, 0, stream>>>(pm, pl, pO, whf, out);
}

// Round 8
// 688.102 us; speedup vs baseline: 1.1975x; 1.1975x over previous
//
#include <hip/hip_runtime.h>
#include <hip/hip_bf16.h>
#include <stdint.h>
#include <math.h>

#define N_NODES 8192
#define FDIM 128
#define LRELU_ALPHA 0.2f
#define BETA 0.3f
#define NEGV -9000000000000000.0f
#define THR 8.0f
#define NJQ 4

typedef __attribute__((ext_vector_type(8))) short bf16x8;
typedef __attribute__((ext_vector_type(4))) float f32x4;
typedef __attribute__((ext_vector_type(4))) long long64x4;

__device__ __forceinline__ uint16_t f2b(float x) {
  union { float f; uint32_t u; } v; v.f = x;
  uint32_t r = v.u + 0x7FFFu + ((v.u >> 16) & 1u);
  return (uint16_t)(r >> 16);
}

// ---------------------------------------------------------------------------
__global__ void __launch_bounds__(256) prep_wh(
    const float* __restrict__ h, const float* __restrict__ w,
    float* __restrict__ whf, uint16_t* __restrict__ whb,
    uint16_t* __restrict__ whtb) {
  __shared__ float hs[32][128];
  const int t = threadIdx.x;
  const int rb = blockIdx.x * 32;
#pragma unroll
  for (int k = 0; k < 16; ++k) {
    int idx = t + k * 256;
    int r = idx >> 7, c = idx & 127;
    hs[r][c] = h[(size_t)(rb + r) * FDIM + c];
  }
  __syncthreads();
  const int c = t & 127;
  const int half = t >> 7;
  const int r0 = half * 16;
  float acc[16];
#pragma unroll
  for (int k = 0; k < 16; ++k) acc[k] = 0.f;
  for (int kk = 0; kk < 128; ++kk) {
    float wv = w[kk * FDIM + c];
#pragma unroll
    for (int k = 0; k < 16; ++k) acc[k] += hs[r0 + k][kk] * wv;
  }
  uint16_t tb[16];
#pragma unroll
  for (int k = 0; k < 16; ++k) {
    int r = rb + r0 + k;
    whf[(size_t)r * FDIM + c] = acc[k];
    uint16_t b = f2b(acc[k]);
    whb[(size_t)r * FDIM + c] = b;
    tb[k] = b;
  }
  uint16_t* dst = whtb + (size_t)c * N_NODES + rb + r0;
  bf16x8 v0, v1;
#pragma unroll
  for (int k = 0; k < 8; ++k) { v0[k] = (short)tb[k]; v1[k] = (short)tb[k + 8]; }
  *(bf16x8*)(dst) = v0;
  *(bf16x8*)(dst + 8) = v1;
}

// ---------------------------------------------------------------------------
__global__ void __launch_bounds__(256) prep_s1(
    const float* __restrict__ whf, const float* __restrict__ a,
    float* __restrict__ s1, uint16_t* __restrict__ a2b) {
  const int t = threadIdx.x;
  const int rb = blockIdx.x * 32;
  const int wv = t >> 6;
  const int lane = t & 63;
  const int r = rb + wv * 8 + (lane >> 3);
  const int c0 = (lane & 7) * 16;
  float s = 0.f;
#pragma unroll
  for (int k = 0; k < 16; ++k) {
    s += whf[(size_t)r * FDIM + c0 + k] * a[(size_t)r * 256 + c0 + k];
  }
  s += __shfl_xor(s, 1);
  s += __shfl_xor(s, 2);
  s += __shfl_xor(s, 4);
  if ((lane & 7) == 0) s1[r] = s;
#pragma unroll
  for (int k = 0; k < 16; ++k) {
    int idx = t + k * 256;
    int rr = idx >> 7, cc = idx & 127;
    a2b[(size_t)(rb + rr) * FDIM + cc] = f2b(a[(size_t)(rb + rr) * 256 + 128 + cc]);
  }
}

// ---------------------------------------------------------------------------
__global__ void __launch_bounds__(256) pack_adj(
    const int* __restrict__ adj, uint32_t* __restrict__ bits) {
  const int wid = (blockIdx.x * 256 + threadIdx.x) >> 6;
  const int lane = threadIdx.x & 63;
  for (int g = 0; g < 128; g += 4) {
    size_t gi = (size_t)wid * 128 + g;
    int v0 = adj[(gi + 0) * 64 + lane];
    int v1 = adj[(gi + 1) * 64 + lane];
    int v2 = adj[(gi + 2) * 64 + lane];
    int v3 = adj[(gi + 3) * 64 + lane];
    unsigned long long m0 = __ballot(v0 > 0);
    unsigned long long m1 = __ballot(v1 > 0);
    unsigned long long m2 = __ballot(v2 > 0);
    unsigned long long m3 = __ballot(v3 > 0);
    if (lane == 0) {
      long64x4 pk;
      pk[0] = (long)m0; pk[1] = (long)m1; pk[2] = (long)m2; pk[3] = (long)m3;
      *(long64x4*)(bits + gi * 2) = pk;
    }
  }
}

// ---------------------------------------------------------------------------
// gat_kernel<MODE>: R6 structure, ablation variants.
//   MODE 0 = full (real output)      MODE 1 = no softmax (p = e)
//   MODE 2 = no PV (no plds/whtb/PV-MFMA)   MODE 3 = no S (no whb/S-MFMA)
//   MODE 4 = no adj loads (unmasked)
// ---------------------------------------------------------------------------
template<int MODE>
__global__ void __launch_bounds__(512, 2) gat_kernel(
    const uint32_t* __restrict__ adjw, const uint16_t* __restrict__ whb,
    const uint16_t* __restrict__ whtb, const uint16_t* __restrict__ a2b,
    const float* __restrict__ s1,
    float* __restrict__ pm, float* __restrict__ pl, float* __restrict__ pO) {
  __shared__ float O_lds[8][16][128];
  __shared__ __align__(16) uint16_t plds[8][32][40];
  __shared__ float m_lds[8][32], l_lds[8][32];
  __shared__ float ew_lds[8][32];

  const int bid = blockIdx.x;
  const int xcd = bid & 7;
  const int jq = xcd >> 1;
  const int ib = ((bid >> 3) << 1) | (xcd & 1);
  const int ibase = ib * 32;
  const int jqb = jq * (N_NODES / NJQ);

  const int tid = threadIdx.x;
  const int wv = tid >> 6;
  const int lane = tid & 63;
  const int ln = lane & 15;
  const int lg = lane >> 4;

  bf16x8 af[2][4];
#pragma unroll
  for (int it = 0; it < 2; ++it)
#pragma unroll
    for (int ks = 0; ks < 4; ++ks)
      af[it][ks] = *(const bf16x8*)(a2b + (size_t)(ibase + it * 16 + ln) * FDIM + ks * 32 + lg * 8);

  float s1v[2][4];
#pragma unroll
  for (int it = 0; it < 2; ++it)
#pragma unroll
    for (int r = 0; r < 4; ++r)
      s1v[it][r] = s1[ibase + it * 16 + lg * 4 + r];

  const uint32_t* adjbase = adjw + (size_t)(ibase + lg * 4) * (N_NODES / 32);

  float mrun[2][4], lsum[2][4];
#pragma unroll
  for (int it = 0; it < 2; ++it)
#pragma unroll
    for (int r = 0; r < 4; ++r) { mrun[it][r] = -INFINITY; lsum[it][r] = 0.f; }
  f32x4 O[2][8];
#pragma unroll
  for (int it = 0; it < 2; ++it)
#pragma unroll
    for (int ft = 0; ft < 8; ++ft) O[it][ft] = (f32x4){0.f, 0.f, 0.f, 0.f};

  const int j0 = jqb + wv * (N_NODES / NJQ / 8);
  for (int jb = j0; jb < j0 + N_NODES / NJQ / 8; jb += 32) {
    const int wi = jb >> 5;
    uint32_t aw[2][4];
    if constexpr (MODE != 4) {
#pragma unroll
      for (int it = 0; it < 2; ++it)
#pragma unroll
        for (int r = 0; r < 4; ++r)
          aw[it][r] = adjbase[(size_t)(it * 16 + r) * (N_NODES / 32) + wi];
    }

    f32x4 sacc[2][2];
#pragma unroll
    for (int it = 0; it < 2; ++it)
#pragma unroll
      for (int nt = 0; nt < 2; ++nt) sacc[it][nt] = (f32x4){0.f, 0.f, 0.f, 0.f};
    if constexpr (MODE != 3) {
#pragma unroll
      for (int nt = 0; nt < 2; ++nt)
#pragma unroll
        for (int ks = 0; ks < 4; ++ks) {
          bf16x8 b = *(const bf16x8*)(whb + (size_t)(jb + nt * 16 + ln) * FDIM + ks * 32 + lg * 8);
          sacc[0][nt] = __builtin_amdgcn_mfma_f32_16x16x32_bf16(af[0][ks], b, sacc[0][nt], 0, 0, 0);
          sacc[1][nt] = __builtin_amdgcn_mfma_f32_16x16x32_bf16(af[1][ks], b, sacc[1][nt], 0, 0, 0);
        }
    }

    float e[2][2][4];
#pragma unroll
    for (int it = 0; it < 2; ++it)
#pragma unroll
      for (int nt = 0; nt < 2; ++nt)
#pragma unroll
        for (int r = 0; r < 4; ++r) {
          float v = s1v[it][r] + sacc[it][nt][r];
          if constexpr (MODE == 3) v += (float)(wi & 7) * 0.1f;  // vary per iter
          v = (v > 0.f) ? v : LRELU_ALPHA * v;
          if constexpr (MODE != 4) {
            uint32_t bit = (aw[it][r] >> (nt * 16 + ln)) & 1u;
            e[it][nt][r] = bit ? v : NEGV;
          } else {
            e[it][nt][r] = v;
          }
        }

    if constexpr (MODE != 1) {
      bool upd = false;
#pragma unroll
      for (int it = 0; it < 2; ++it)
#pragma unroll
        for (int r = 0; r < 4; ++r)
          upd |= (e[it][0][r] > mrun[it][r] + THR) || (e[it][1][r] > mrun[it][r] + THR);
      if (__any(upd)) {
#pragma unroll
        for (int it = 0; it < 2; ++it) {
          float mx[4];
#pragma unroll
          for (int r = 0; r < 4; ++r) mx[r] = fmaxf(e[it][0][r], e[it][1][r]);
#pragma unroll
          for (int off = 1; off <= 8; off <<= 1)
#pragma unroll
            for (int r = 0; r < 4; ++r) mx[r] = fmaxf(mx[r], __shfl_xor(mx[r], off));
#pragma unroll
          for (int r = 0; r < 4; ++r) {
            float mn = fmaxf(mrun[it][r], mx[r]);
            float al = __expf(mrun[it][r] - mn);
            mrun[it][r] = mn;
            lsum[it][r] *= al;
#pragma unroll
            for (int ft = 0; ft < 8; ++ft) O[it][ft][r] *= al;
          }
        }
      }
    }

#pragma unroll
    for (int it = 0; it < 2; ++it)
#pragma unroll
      for (int nt = 0; nt < 2; ++nt)
#pragma unroll
        for (int r = 0; r < 4; ++r) {
          float p;
          if constexpr (MODE == 1) p = e[it][nt][r];
          else                     p = __expf(e[it][nt][r] - mrun[it][r]);
          lsum[it][r] += p;
          if constexpr (MODE != 2)
            plds[wv][it * 16 + lg * 4 + r][nt * 16 + ln] = f2b(p);
        }

    if constexpr (MODE != 2) {
      bf16x8 pa0 = *(const bf16x8*)&plds[wv][ln][lg * 8];
      bf16x8 pa1 = *(const bf16x8*)&plds[wv][16 + ln][lg * 8];
#pragma unroll
      for (int ft = 0; ft < 8; ++ft) {
        bf16x8 bv = *(const bf16x8*)(whtb + (size_t)(ft * 16 + ln) * N_NODES + jb + lg * 8);
        O[0][ft] = __builtin_amdgcn_mfma_f32_16x16x32_bf16(pa0, bv, O[0][ft], 0, 0, 0);
        O[1][ft] = __builtin_amdgcn_mfma_f32_16x16x32_bf16(pa1, bv, O[1][ft], 0, 0, 0);
      }
    }
  }

#pragma unroll
  for (int off = 1; off <= 8; off <<= 1)
#pragma unroll
    for (int it = 0; it < 2; ++it)
#pragma unroll
      for (int r = 0; r < 4; ++r) lsum[it][r] += __shfl_xor(lsum[it][r], off);

  if (ln == 0) {
#pragma unroll
    for (int it = 0; it < 2; ++it)
#pragma unroll
      for (int r = 0; r < 4; ++r) {
        m_lds[wv][it * 16 + lg * 4 + r] = mrun[it][r];
        l_lds[wv][it * 16 + lg * 4 + r] = lsum[it][r];
      }
  }
  __syncthreads();

  if (tid < 32) {
    float ms = -INFINITY;
#pragma unroll
    for (int w2 = 0; w2 < 8; ++w2) ms = fmaxf(ms, m_lds[w2][tid]);
    float L = 0.f;
#pragma unroll
    for (int w2 = 0; w2 < 8; ++w2) {
      float x = __expf(m_lds[w2][tid] - ms);
      ew_lds[w2][tid] = x;
      L += l_lds[w2][tid] * x;
    }
    pm[(size_t)jq * N_NODES + ibase + tid] = ms;
    pl[(size_t)jq * N_NODES + ibase + tid] = L;
  }
  __syncthreads();

#pragma unroll
  for (int h = 0; h < 2; ++h) {
#pragma unroll
    for (int ft = 0; ft < 8; ++ft)
#pragma unroll
      for (int r = 0; r < 4; ++r)
        O_lds[wv][lg * 4 + r][ft * 16 + ln] = O[h][ft][r];
    __syncthreads();
#pragma unroll
    for (int k = 0; k < 4; ++k) {
      int idx = tid + k * 512;
      int r = idx >> 7, f = idx & 127;
      float v = 0.f;
#pragma unroll
      for (int w2 = 0; w2 < 8; ++w2) v += O_lds[w2][r][f] * ew_lds[w2][h * 16 + r];
      int row = ibase + h * 16 + r;
      pO[((size_t)jq * N_NODES + row) * FDIM + f] = v;
    }
    if (h == 0) __syncthreads();
  }
}

// ---------------------------------------------------------------------------
__global__ void __launch_bounds__(256) merge_out(
    const float* __restrict__ pm, const float* __restrict__ pl,
    const float* __restrict__ pO, const float* __restrict__ whf,
    float* __restrict__ out) {
  const int idx = blockIdx.x * 256 + threadIdx.x;
  const int row = idx >> 7;
  float m[NJQ];
#pragma unroll
  for (int q = 0; q < NJQ; ++q) m[q] = pm[q * N_NODES + row];
  float M = fmaxf(fmaxf(m[0], m[1]), fmaxf(m[2], m[3]));
  float ew[NJQ];
  float L = 0.f;
#pragma unroll
  for (int q = 0; q < NJQ; ++q) {
    ew[q] = __expf(m[q] - M);
    L += pl[q * N_NODES + row] * ew[q];
  }
  float v = 0.f;
#pragma unroll
  for (int q = 0; q < NJQ; ++q)
    v += pO[(size_t)q * N_NODES * FDIM + idx] * ew[q];
  v /= L;
  v += BETA * whf[idx];
  out[idx] = (v > 0.f) ? v : (__expf(v) - 1.0f);
}

// ---------------------------------------------------------------------------
extern "C" void kernel_launch(void* const* d_in, const int* in_sizes, int n_in,
                              void* d_out, int out_size, void* d_ws, size_t ws_size,
                              hipStream_t stream) {
  const float* h   = (const float*)d_in[0];
  const int*   adj = (const int*)d_in[1];
  const float* w   = (const float*)d_in[3];
  const float* a   = (const float*)d_in[4];
  float* out = (float*)d_out;

  char* ws = (char*)d_ws;
  float*    whf  = (float*)ws;
  uint16_t* whb  = (uint16_t*)(ws + (4 << 20));
  uint16_t* whtb = (uint16_t*)(ws + (6 << 20));
  uint16_t* a2b  = (uint16_t*)(ws + (8 << 20));
  float*    s1   = (float*)(ws + (10 << 20));
  uint32_t* adjw = (uint32_t*)(ws + (10 << 20) + (1 << 19));
  float*    pm   = (float*)(ws + (18 << 20) + (1 << 19));
  float*    pl   = (float*)(ws + (18 << 20) + (1 << 19) + (1 << 17));
  float*    pO   = (float*)(ws + (19 << 20));

  prep_wh<<<N_NODES / 32, 256, 0, stream>>>(h, w, whf, whb, whtb);
  prep_s1<<<N_NODES / 32, 256, 0, stream>>>(whf, a, s1, a2b);
  pack_adj<<<2048, 256, 0, stream>>>(adj, adjw);

  const int G = (N_NODES / 32) * NJQ;
  // ablation variants (scratch results; overwritten by <0> below)
  gat_kernel<1><<<G, 512, 0, stream>>>(adjw, whb, whtb, a2b, s1, pm, pl, pO);
  gat_kernel<2><<<G, 512, 0, stream>>>(adjw, whb, whtb, a2b, s1, pm, pl, pO);
  gat_kernel<3><<<G, 512, 0, stream>>>(adjw, whb, whtb, a2b, s1, pm, pl, pO);
  gat_kernel<4><<<G, 512, 0, stream>>>(adjw, whb, whtb, a2b, s1, pm, pl, pO);
  // real pass
  gat_kernel<0><<<G, 512, 0, stream>>>(adjw, whb, whtb, a2b, s1, pm, pl, pO);
  merge_out<<<N_NODES * FDIM / 256, 256, 0, stream>>>(pm, pl, pO, whf, out);
}

// Round 9
// 231.444 us; speedup vs baseline: 3.5603x; 2.9731x over previous
//
#include <hip/hip_runtime.h>
#include <hip/hip_bf16.h>
#include <stdint.h>
#include <math.h>

#define N_NODES 8192
#define FDIM 128
#define LRELU_ALPHA 0.2f
#define BETA 0.3f
#define NEGV -9000000000000000.0f
#define THR 8.0f
#define NJQ 4

typedef __attribute__((ext_vector_type(8))) short bf16x8;
typedef __attribute__((ext_vector_type(4))) float f32x4;
typedef __attribute__((ext_vector_type(4))) long long64x4;

__device__ __forceinline__ uint16_t f2b(float x) {
  union { float f; uint32_t u; } v; v.f = x;
  uint32_t r = v.u + 0x7FFFu + ((v.u >> 16) & 1u);
  return (uint16_t)(r >> 16);
}

// ---------------------------------------------------------------------------
__global__ void __launch_bounds__(256) prep_wh(
    const float* __restrict__ h, const float* __restrict__ w,
    float* __restrict__ whf, uint16_t* __restrict__ whb,
    uint16_t* __restrict__ whtb) {
  __shared__ float hs[32][128];
  const int t = threadIdx.x;
  const int rb = blockIdx.x * 32;
#pragma unroll
  for (int k = 0; k < 16; ++k) {
    int idx = t + k * 256;
    int r = idx >> 7, c = idx & 127;
    hs[r][c] = h[(size_t)(rb + r) * FDIM + c];
  }
  __syncthreads();
  const int c = t & 127;
  const int half = t >> 7;
  const int r0 = half * 16;
  float acc[16];
#pragma unroll
  for (int k = 0; k < 16; ++k) acc[k] = 0.f;
  for (int kk = 0; kk < 128; ++kk) {
    float wv = w[kk * FDIM + c];
#pragma unroll
    for (int k = 0; k < 16; ++k) acc[k] += hs[r0 + k][kk] * wv;
  }
  uint16_t tb[16];
#pragma unroll
  for (int k = 0; k < 16; ++k) {
    int r = rb + r0 + k;
    whf[(size_t)r * FDIM + c] = acc[k];
    uint16_t b = f2b(acc[k]);
    whb[(size_t)r * FDIM + c] = b;
    tb[k] = b;
  }
  uint16_t* dst = whtb + (size_t)c * N_NODES + rb + r0;
  bf16x8 v0, v1;
#pragma unroll
  for (int k = 0; k < 8; ++k) { v0[k] = (short)tb[k]; v1[k] = (short)tb[k + 8]; }
  *(bf16x8*)(dst) = v0;
  *(bf16x8*)(dst + 8) = v1;
}

// ---------------------------------------------------------------------------
__global__ void __launch_bounds__(256) prep_s1(
    const float* __restrict__ whf, const float* __restrict__ a,
    float* __restrict__ s1, uint16_t* __restrict__ a2b) {
  const int t = threadIdx.x;
  const int rb = blockIdx.x * 32;
  const int wv = t >> 6;
  const int lane = t & 63;
  const int r = rb + wv * 8 + (lane >> 3);
  const int c0 = (lane & 7) * 16;
  float s = 0.f;
#pragma unroll
  for (int k = 0; k < 16; ++k) {
    s += whf[(size_t)r * FDIM + c0 + k] * a[(size_t)r * 256 + c0 + k];
  }
  s += __shfl_xor(s, 1);
  s += __shfl_xor(s, 2);
  s += __shfl_xor(s, 4);
  if ((lane & 7) == 0) s1[r] = s;
#pragma unroll
  for (int k = 0; k < 16; ++k) {
    int idx = t + k * 256;
    int rr = idx >> 7, cc = idx & 127;
    a2b[(size_t)(rb + rr) * FDIM + cc] = f2b(a[(size_t)(rb + rr) * 256 + 128 + cc]);
  }
}

// ---------------------------------------------------------------------------
__global__ void __launch_bounds__(256) pack_adj(
    const int* __restrict__ adj, uint32_t* __restrict__ bits) {
  const int wid = (blockIdx.x * 256 + threadIdx.x) >> 6;
  const int lane = threadIdx.x & 63;
  for (int g = 0; g < 128; g += 4) {
    size_t gi = (size_t)wid * 128 + g;
    int v0 = adj[(gi + 0) * 64 + lane];
    int v1 = adj[(gi + 1) * 64 + lane];
    int v2 = adj[(gi + 2) * 64 + lane];
    int v3 = adj[(gi + 3) * 64 + lane];
    unsigned long long m0 = __ballot(v0 > 0);
    unsigned long long m1 = __ballot(v1 > 0);
    unsigned long long m2 = __ballot(v2 > 0);
    unsigned long long m3 = __ballot(v3 > 0);
    if (lane == 0) {
      long64x4 pk;
      pk[0] = (long)m0; pk[1] = (long)m1; pk[2] = (long)m2; pk[3] = (long)m3;
      *(long64x4*)(bits + gi * 2) = pk;
    }
  }
}

// ---------------------------------------------------------------------------
// gat_main: R6 main loop, LDS trimmed to ~56KB (32KB O_lds, 4-pass merge)
// so 2 blocks/CU are resident; __launch_bounds__(512,2) keeps VGPR=128
// (no spill; 128 VGPR allows exactly 4 waves/SIMD).
// grid 1024 blocks x 512 thr.
// ---------------------------------------------------------------------------
__global__ void __launch_bounds__(512, 2) gat_main(
    const uint32_t* __restrict__ adjw, const uint16_t* __restrict__ whb,
    const uint16_t* __restrict__ whtb, const uint16_t* __restrict__ a2b,
    const float* __restrict__ s1,
    float* __restrict__ pm, float* __restrict__ pl, float* __restrict__ pO) {
  __shared__ float O_lds[8][16][64];                     // 32 KB (4-pass merge)
  __shared__ __align__(16) uint16_t plds[8][32][40];     // 20.5 KB, pitch 80B
  __shared__ float m_lds[8][32], l_lds[8][32];
  __shared__ float ew_lds[8][32];

  const int bid = blockIdx.x;
  const int xcd = bid & 7;
  const int jq = xcd >> 1;
  const int ib = ((bid >> 3) << 1) | (xcd & 1);
  const int ibase = ib * 32;
  const int jqb = jq * (N_NODES / NJQ);

  const int tid = threadIdx.x;
  const int wv = tid >> 6;
  const int lane = tid & 63;
  const int ln = lane & 15;
  const int lg = lane >> 4;

  bf16x8 af[2][4];
#pragma unroll
  for (int it = 0; it < 2; ++it)
#pragma unroll
    for (int ks = 0; ks < 4; ++ks)
      af[it][ks] = *(const bf16x8*)(a2b + (size_t)(ibase + it * 16 + ln) * FDIM + ks * 32 + lg * 8);

  float s1v[2][4];
#pragma unroll
  for (int it = 0; it < 2; ++it)
#pragma unroll
    for (int r = 0; r < 4; ++r)
      s1v[it][r] = s1[ibase + it * 16 + lg * 4 + r];

  const uint32_t* adjbase = adjw + (size_t)(ibase + lg * 4) * (N_NODES / 32);

  float mrun[2][4], lsum[2][4];
#pragma unroll
  for (int it = 0; it < 2; ++it)
#pragma unroll
    for (int r = 0; r < 4; ++r) { mrun[it][r] = -INFINITY; lsum[it][r] = 0.f; }
  f32x4 O[2][8];
#pragma unroll
  for (int it = 0; it < 2; ++it)
#pragma unroll
    for (int ft = 0; ft < 8; ++ft) O[it][ft] = (f32x4){0.f, 0.f, 0.f, 0.f};

  const int j0 = jqb + wv * (N_NODES / NJQ / 8);          // 256 j per wave
  for (int jb = j0; jb < j0 + N_NODES / NJQ / 8; jb += 32) {
    const int wi = jb >> 5;
    uint32_t aw[2][4];
#pragma unroll
    for (int it = 0; it < 2; ++it)
#pragma unroll
      for (int r = 0; r < 4; ++r)
        aw[it][r] = adjbase[(size_t)(it * 16 + r) * (N_NODES / 32) + wi];

    f32x4 sacc[2][2];
#pragma unroll
    for (int it = 0; it < 2; ++it)
#pragma unroll
      for (int nt = 0; nt < 2; ++nt) sacc[it][nt] = (f32x4){0.f, 0.f, 0.f, 0.f};
#pragma unroll
    for (int nt = 0; nt < 2; ++nt)
#pragma unroll
      for (int ks = 0; ks < 4; ++ks) {
        bf16x8 b = *(const bf16x8*)(whb + (size_t)(jb + nt * 16 + ln) * FDIM + ks * 32 + lg * 8);
        sacc[0][nt] = __builtin_amdgcn_mfma_f32_16x16x32_bf16(af[0][ks], b, sacc[0][nt], 0, 0, 0);
        sacc[1][nt] = __builtin_amdgcn_mfma_f32_16x16x32_bf16(af[1][ks], b, sacc[1][nt], 0, 0, 0);
      }

    float e[2][2][4];
#pragma unroll
    for (int it = 0; it < 2; ++it)
#pragma unroll
      for (int nt = 0; nt < 2; ++nt)
#pragma unroll
        for (int r = 0; r < 4; ++r) {
          float v = s1v[it][r] + sacc[it][nt][r];
          v = (v > 0.f) ? v : LRELU_ALPHA * v;
          uint32_t bit = (aw[it][r] >> (nt * 16 + ln)) & 1u;
          e[it][nt][r] = bit ? v : NEGV;
        }

    bool upd = false;
#pragma unroll
    for (int it = 0; it < 2; ++it)
#pragma unroll
      for (int r = 0; r < 4; ++r)
        upd |= (e[it][0][r] > mrun[it][r] + THR) || (e[it][1][r] > mrun[it][r] + THR);
    if (__any(upd)) {
#pragma unroll
      for (int it = 0; it < 2; ++it) {
        float mx[4];
#pragma unroll
        for (int r = 0; r < 4; ++r) mx[r] = fmaxf(e[it][0][r], e[it][1][r]);
#pragma unroll
        for (int off = 1; off <= 8; off <<= 1)
#pragma unroll
          for (int r = 0; r < 4; ++r) mx[r] = fmaxf(mx[r], __shfl_xor(mx[r], off));
#pragma unroll
        for (int r = 0; r < 4; ++r) {
          float mn = fmaxf(mrun[it][r], mx[r]);
          float al = __expf(mrun[it][r] - mn);
          mrun[it][r] = mn;
          lsum[it][r] *= al;
#pragma unroll
          for (int ft = 0; ft < 8; ++ft) O[it][ft][r] *= al;
        }
      }
    }

#pragma unroll
    for (int it = 0; it < 2; ++it)
#pragma unroll
      for (int nt = 0; nt < 2; ++nt)
#pragma unroll
        for (int r = 0; r < 4; ++r) {
          float p = __expf(e[it][nt][r] - mrun[it][r]);
          lsum[it][r] += p;
          plds[wv][it * 16 + lg * 4 + r][nt * 16 + ln] = f2b(p);
        }

    bf16x8 pa0 = *(const bf16x8*)&plds[wv][ln][lg * 8];
    bf16x8 pa1 = *(const bf16x8*)&plds[wv][16 + ln][lg * 8];

#pragma unroll
    for (int ft = 0; ft < 8; ++ft) {
      bf16x8 bv = *(const bf16x8*)(whtb + (size_t)(ft * 16 + ln) * N_NODES + jb + lg * 8);
      O[0][ft] = __builtin_amdgcn_mfma_f32_16x16x32_bf16(pa0, bv, O[0][ft], 0, 0, 0);
      O[1][ft] = __builtin_amdgcn_mfma_f32_16x16x32_bf16(pa1, bv, O[1][ft], 0, 0, 0);
    }
  }

#pragma unroll
  for (int off = 1; off <= 8; off <<= 1)
#pragma unroll
    for (int it = 0; it < 2; ++it)
#pragma unroll
      for (int r = 0; r < 4; ++r) lsum[it][r] += __shfl_xor(lsum[it][r], off);

  if (ln == 0) {
#pragma unroll
    for (int it = 0; it < 2; ++it)
#pragma unroll
      for (int r = 0; r < 4; ++r) {
        m_lds[wv][it * 16 + lg * 4 + r] = mrun[it][r];
        l_lds[wv][it * 16 + lg * 4 + r] = lsum[it][r];
      }
  }
  __syncthreads();

  if (tid < 32) {
    float ms = -INFINITY;
#pragma unroll
    for (int w2 = 0; w2 < 8; ++w2) ms = fmaxf(ms, m_lds[w2][tid]);
    float L = 0.f;
#pragma unroll
    for (int w2 = 0; w2 < 8; ++w2) {
      float x = __expf(m_lds[w2][tid] - ms);
      ew_lds[w2][tid] = x;
      L += l_lds[w2][tid] * x;
    }
    pm[(size_t)jq * N_NODES + ibase + tid] = ms;
    pl[(size_t)jq * N_NODES + ibase + tid] = L;
  }
  __syncthreads();

  // 4-pass merge: 2 row-halves (h) x 2 column-halves (cg), 16x64 per pass.
#pragma unroll
  for (int h = 0; h < 2; ++h)
#pragma unroll
    for (int cg = 0; cg < 2; ++cg) {
#pragma unroll
      for (int f2 = 0; f2 < 4; ++f2)
#pragma unroll
        for (int r = 0; r < 4; ++r)
          O_lds[wv][lg * 4 + r][f2 * 16 + ln] = O[h][cg * 4 + f2][r];
      __syncthreads();
#pragma unroll
      for (int k = 0; k < 2; ++k) {
        int idx = tid + k * 512;          // 0..1023 = 16 rows x 64
        int r = idx >> 6, f = idx & 63;
        float v = 0.f;
#pragma unroll
        for (int w2 = 0; w2 < 8; ++w2) v += O_lds[w2][r][f] * ew_lds[w2][h * 16 + r];
        int row = ibase + h * 16 + r;
        pO[((size_t)jq * N_NODES + row) * FDIM + cg * 64 + f] = v;
      }
      __syncthreads();
    }
}

// ---------------------------------------------------------------------------
__global__ void __launch_bounds__(256) merge_out(
    const float* __restrict__ pm, const float* __restrict__ pl,
    const float* __restrict__ pO, const float* __restrict__ whf,
    float* __restrict__ out) {
  const int idx = blockIdx.x * 256 + threadIdx.x;
  const int row = idx >> 7;
  float m[NJQ];
#pragma unroll
  for (int q = 0; q < NJQ; ++q) m[q] = pm[q * N_NODES + row];
  float M = fmaxf(fmaxf(m[0], m[1]), fmaxf(m[2], m[3]));
  float ew[NJQ];
  float L = 0.f;
#pragma unroll
  for (int q = 0; q < NJQ; ++q) {
    ew[q] = __expf(m[q] - M);
    L += pl[q * N_NODES + row] * ew[q];
  }
  float v = 0.f;
#pragma unroll
  for (int q = 0; q < NJQ; ++q)
    v += pO[(size_t)q * N_NODES * FDIM + idx] * ew[q];
  v /= L;
  v += BETA * whf[idx];
  out[idx] = (v > 0.f) ? v : (__expf(v) - 1.0f);
}

// ---------------------------------------------------------------------------
extern "C" void kernel_launch(void* const* d_in, const int* in_sizes, int n_in,
                              void* d_out, int out_size, void* d_ws, size_t ws_size,
                              hipStream_t stream) {
  const float* h   = (const float*)d_in[0];
  const int*   adj = (const int*)d_in[1];
  const float* w   = (const float*)d_in[3];
  const float* a   = (const float*)d_in[4];
  float* out = (float*)d_out;

  char* ws = (char*)d_ws;
  float*    whf  = (float*)ws;                               // 4 MB
  uint16_t* whb  = (uint16_t*)(ws + (4 << 20));              // 2 MB
  uint16_t* whtb = (uint16_t*)(ws + (6 << 20));              // 2 MB
  uint16_t* a2b  = (uint16_t*)(ws + (8 << 20));              // 2 MB
  float*    s1   = (float*)(ws + (10 << 20));                // 32 KB
  uint32_t* adjw = (uint32_t*)(ws + (10 << 20) + (1 << 19)); // 8 MB bitmask
  float*    pm   = (float*)(ws + (18 << 20) + (1 << 19));    // 128 KB
  float*    pl   = (float*)(ws + (18 << 20) + (1 << 19) + (1 << 17)); // 128 KB
  float*    pO   = (float*)(ws + (19 << 20));                // 16 MB

  prep_wh<<<N_NODES / 32, 256, 0, stream>>>(h, w, whf, whb, whtb);
  prep_s1<<<N_NODES / 32, 256, 0, stream>>>(whf, a, s1, a2b);
  pack_adj<<<2048, 256, 0, stream>>>(adj, adjw);
  gat_main<<<(N_NODES / 32) * NJQ, 512, 0, stream>>>(adjw, whb, whtb, a2b, s1, pm, pl, pO);
  merge_out<<<N_NODES * FDIM / 256, 256, 0, stream>>>(pm, pl, pO, whf, out);
}